// Round 6
// baseline (297.307 us; speedup 1.0000x reference)
//
#include <hip/hip_runtime.h>

typedef __bf16 bf16x8 __attribute__((ext_vector_type(8)));
typedef float f32x16 __attribute__((ext_vector_type(16)));

__device__ __forceinline__ unsigned short f2bf(float f) {
    union { float f; unsigned u; } v; v.f = f;
    unsigned r = (v.u + 0x7FFFu + ((v.u >> 16) & 1u)) >> 16;
    return (unsigned short)r;
}
// pack two f32 -> one u32 of 2x bf16 (RNE; compiler fuses to v_cvt_pk_bf16_f32)
__device__ __forceinline__ unsigned pk2(float lo, float hi) {
    union { unsigned u; __bf16 h[2]; } t;
    t.h[0] = (__bf16)lo; t.h[1] = (__bf16)hi; return t.u;
}

// ---- weight conversion into MFMA fragment order (32x32x16 bf16) ----
// Frag mapping: lane l holds W[k0 + (l>>5)*8 + j][n0 + (l&31)], j=0..7.
// W1F index = ((g*8 + kb)*64 + l)*8 + j   (g: hidden col-group 0..31, kb: K-step 0..7, K pad 119->128)
// W2F index = ((gn*64 + kb)*64 + l)*8 + j (gn: out col-group 0..7, kb: K-step 0..63)
__global__ void conv_w(const float* __restrict__ W1, const float* __restrict__ W2,
                       unsigned short* __restrict__ W1F, unsigned short* __restrict__ W2F) {
    int b = blockIdx.x;
    if (b < 512) {
        int idx = b * 256 + threadIdx.x;                   // 131072
        int j = idx & 7, l = (idx >> 3) & 63, kb = (idx >> 9) & 7, g = idx >> 12;
        int k = kb * 16 + (l >> 5) * 8 + j;
        int h = g * 32 + (l & 31);
        float v = (k < 119) ? W1[(size_t)k * 1024 + h] : 0.0f;
        W1F[idx] = f2bf(v);
    } else {
        int idx = (b - 512) * 256 + threadIdx.x;           // 262144
        int j = idx & 7, l = (idx >> 3) & 63, kb = (idx >> 9) & 63, gn = idx >> 15;
        int k = kb * 16 + (l >> 5) * 8 + j;
        int n = gn * 32 + (l & 31);
        W2F[idx] = f2bf(W2[(size_t)k * 256 + n]);
    }
}

// ---- fused features + MLP ----
// 256 threads (4 waves), 64 rows/block, grid 2048. chunk = 128 hidden cols (8 chunks).
// R2's compiler-scheduled pipeline (no sched_barrier, no vmcnt pinning, dbuf H, ONE
// barrier/chunk, W2 frags prefetched into regs before the barrier) + R5's fully
// fragment-ordered LDS (all main-loop LDS at addr = base + lane*16: zero conflicts).
// New: each wave keeps its own packswap output (A-frags for kc {2w,2w+1}) in registers
// and skips those 4 of 16 H ds_reads per chunk (uniform branch via readfirstlane).
__global__ __launch_bounds__(256, 2) void mlp_fused(
    const float* __restrict__ hole, const float* __restrict__ board,
    const float* __restrict__ b1, const float* __restrict__ b2,
    const unsigned short* __restrict__ W1F, const unsigned short* __restrict__ W2F,
    float* __restrict__ out)
{
    __shared__ unsigned short Xsf[16 * 512];   // 16KB frag-ordered X: ((mi*8+ks)*64+lane)*8
    __shared__ unsigned short HsF[32 * 512];   // 32KB frag-ordered H, dbuf: ((par*16+mi*8+kc)*64+lane)*8
    // rowmajX (64 rows x 128 shorts) aliases HsF[0..8191] during init only

    const int tid  = threadIdx.x;
    const int w    = tid >> 6;
    const int lane = tid & 63;
    const int l32  = lane & 31;
    const int hi   = lane >> 5;      // 0/1 half-wave
    const long r0  = (long)blockIdx.x * 64;
    const int crot = (int)((blockIdx.x + (blockIdx.x >> 8)) & 7);

    // ---------------- feature extraction: thread t < 64 handles row r0+t ----------------
    if (tid < 64) {
        const long r = r0 + tid;
        const float4* hp = (const float4*)(hole + r * 52);
        const float4* bp = (const float4*)(board + r * 52);
        unsigned long long hm = 0ull, bm = 0ull;
        #pragma unroll
        for (int i = 0; i < 13; ++i) {
            float4 h4 = hp[i], b4 = bp[i];
            int base = i * 4;
            hm |= ((unsigned long long)(h4.x > 0.5f)) << (base + 0);
            hm |= ((unsigned long long)(h4.y > 0.5f)) << (base + 1);
            hm |= ((unsigned long long)(h4.z > 0.5f)) << (base + 2);
            hm |= ((unsigned long long)(h4.w > 0.5f)) << (base + 3);
            bm |= ((unsigned long long)(b4.x > 0.5f)) << (base + 0);
            bm |= ((unsigned long long)(b4.y > 0.5f)) << (base + 1);
            bm |= ((unsigned long long)(b4.z > 0.5f)) << (base + 2);
            bm |= ((unsigned long long)(b4.w > 0.5f)) << (base + 3);
        }
        const unsigned long long am = hm | bm;
        const int bcount = __popcll(bm);
        const int hcount = __popcll(hm);

        int pairs_b = 0, pairs_a = 0;
        bool trips_b = false, trips_a = false;
        unsigned prb = 0, pra = 0;
        #pragma unroll
        for (int rr = 0; rr < 13; ++rr) {
            int cb = __popc((unsigned)((bm >> (4 * rr)) & 0xFull));
            int ca = __popc((unsigned)((am >> (4 * rr)) & 0xFull));
            pairs_b += (cb >= 2); trips_b = trips_b || (cb >= 3); prb |= (unsigned)(cb > 0) << rr;
            pairs_a += (ca >= 2); trips_a = trips_a || (ca >= 3); pra |= (unsigned)(ca > 0) << rr;
        }
        const unsigned long long SM = 0x1111111111111ull;
        int bscm = 0, ascm = 0;
        #pragma unroll
        for (int s = 0; s < 4; ++s) {
            int bs = __popcll(bm & (SM << s));
            int as = __popcll(am & (SM << s));
            bscm = bs > bscm ? bs : bscm;
            ascm = as > ascm ? as : ascm;
        }
        float strength = trips_b ? 0.8f : (pairs_b >= 2 ? 0.6f : (pairs_b >= 1 ? 0.4f : 0.2f));
        if (bcount == 0) strength = 0.0f;
        float flush_b = (bscm >= 3 && bcount > 0) ? 1.0f : 0.0f;
        bool sb = false;
        #pragma unroll
        for (int i = 0; i < 13; ++i) sb = sb || (__popc((prb >> i) & 0x1Fu) >= 3);
        float straight_b = (sb && bcount > 0) ? 1.0f : 0.0f;
        float gr0 = (bcount == 0) ? 1.0f : 0.0f;
        float gr3 = (bcount == 3) ? 1.0f : 0.0f;
        float gr4 = (bcount == 4) ? 1.0f : 0.0f;
        float gr5 = (bcount == 5) ? 1.0f : 0.0f;
        float valid = (hcount >= 2 && bcount >= 1) ? 1.0f : 0.0f;
        float flush_draw = (ascm == 4) ? 1.0f : 0.0f;
        float flush_outs = fmaxf(0.0f, 13.0f - (float)ascm) * (1.0f / 13.0f);
        int first = -1;
        #pragma unroll
        for (int i = 0; i < 13; ++i) {
            bool qq = (((pra >> i) & 1u) != 0u) && (__popc((pra >> i) & 0x1Fu) >= 4);
            if (qq && first < 0) first = i;
        }
        float straight_draw = (first >= 0) ? 1.0f : 0.0f;
        float straight_outs = 0.0f;
        if (first >= 0) {
            int c4 = __popc((pra >> first) & 0xFu);
            straight_outs = (c4 >= 4) ? 0.4f : 0.2f;
        }
        float total_outs = flush_draw * flush_outs * 9.0f + straight_draw * straight_outs * 8.0f;
        float remaining = 52.0f - (float)(hcount + bcount);
        float equity = 0.0f;
        if (remaining > 0.0f) equity = fminf(1.0f, total_outs / fmaxf(remaining, 1.0f));
        float hit_pair  = (pairs_a >= 1) ? 1.0f : 0.0f;
        float hit_trips = trips_a ? 1.0f : 0.0f;
        float hit_two   = (pairs_a >= 2) ? 1.0f : 0.0f;

        unsigned short* xrow = &HsF[tid * 128];    // row-major X temp (aliases HsF par0)
        #pragma unroll
        for (int i = 0; i < 52; ++i) xrow[i]      = ((hm >> i) & 1ull) ? (unsigned short)0x3F80 : (unsigned short)0;
        #pragma unroll
        for (int i = 0; i < 52; ++i) xrow[52 + i] = ((bm >> i) & 1ull) ? (unsigned short)0x3F80 : (unsigned short)0;
        float feats[15] = { strength, flush_b, straight_b, gr0, gr3, gr4, gr5,
                            valid * flush_draw, valid * flush_outs, valid * straight_draw,
                            valid * straight_outs, valid * equity,
                            valid * hit_pair, valid * hit_trips, valid * hit_two };
        #pragma unroll
        for (int i = 0; i < 15; ++i) xrow[104 + i] = f2bf(feats[i]);
        #pragma unroll
        for (int i = 119; i < 128; ++i) xrow[i] = 0;
    }

    f32x16 acc[2][2];
    #pragma unroll
    for (int a = 0; a < 2; ++a)
        #pragma unroll
        for (int b = 0; b < 2; ++b)
            #pragma unroll
            for (int r = 0; r < 16; ++r) acc[a][b][r] = 0.0f;

    __syncthreads();   // rowmajX visible

    // ---- one-time conversion: row-major X -> frag-ordered Xsf (wave w builds ks={2w,2w+1}) ----
    bf16x8 cf[2][2];
    #pragma unroll
    for (int mi = 0; mi < 2; ++mi)
        #pragma unroll
        for (int jj = 0; jj < 2; ++jj) {
            const int ks = 2 * w + jj;
            cf[mi][jj] = *(const bf16x8*)&HsF[(mi * 32 + l32) * 128 + ks * 16 + hi * 8];
        }
    __syncthreads();   // all conversion reads of rowmajX done (HsF free for H)
    #pragma unroll
    for (int mi = 0; mi < 2; ++mi)
        #pragma unroll
        for (int jj = 0; jj < 2; ++jj)
            *(bf16x8*)&Xsf[((mi * 8 + 2 * w + jj) * 64 + lane) * 8] = cf[mi][jj];
    __syncthreads();   // Xsf visible

    const int wu = __builtin_amdgcn_readfirstlane(w);   // wave-uniform wave id (scalar branch)

    f32x16 h0, h1;
    uint4 f00, f01, f10, f11;    // own A-frags: (mi, kc=2w+jj) of the chunk just produced
    float4 wf2r[16];             // W2 frags for next phase B: [kc]=n-group 2w, [8+kc]=2w+1

    // pack h_acc (H^T: m in lane, h in regs) + bias/relu, then lane^32 exchange ->
    // phase-B A-frag pair (kc 2w+0 / 2w+1): lane l holds H[m=l&31][h=kc*16+(l>>5)*8+j]
    auto packswap = [&](const f32x16& h, const float4* bq, uint4& f0, uint4& f1) {
        float v[16];
        #pragma unroll
        for (int q = 0; q < 4; ++q) {
            v[4 * q + 0] = fmaxf(h[4 * q + 0] + bq[q].x, 0.0f);
            v[4 * q + 1] = fmaxf(h[4 * q + 1] + bq[q].y, 0.0f);
            v[4 * q + 2] = fmaxf(h[4 * q + 2] + bq[q].z, 0.0f);
            v[4 * q + 3] = fmaxf(h[4 * q + 3] + bq[q].w, 0.0f);
        }
        unsigned p0 = pk2(v[0], v[1]),  p1 = pk2(v[2], v[3]);
        unsigned p2 = pk2(v[4], v[5]),  p3 = pk2(v[6], v[7]);
        unsigned p4 = pk2(v[8], v[9]),  p5 = pk2(v[10], v[11]);
        unsigned p6 = pk2(v[12], v[13]), p7 = pk2(v[14], v[15]);
        unsigned q0 = (unsigned)__shfl_xor((int)p0, 32, 64);
        unsigned q1 = (unsigned)__shfl_xor((int)p1, 32, 64);
        unsigned q2 = (unsigned)__shfl_xor((int)p2, 32, 64);
        unsigned q3 = (unsigned)__shfl_xor((int)p3, 32, 64);
        unsigned q4 = (unsigned)__shfl_xor((int)p4, 32, 64);
        unsigned q5 = (unsigned)__shfl_xor((int)p5, 32, 64);
        unsigned q6 = (unsigned)__shfl_xor((int)p6, 32, 64);
        unsigned q7 = (unsigned)__shfl_xor((int)p7, 32, 64);
        f0.x = hi ? q2 : p0;  f0.y = hi ? q3 : p1;  f0.z = hi ? p2 : q0;  f0.w = hi ? p3 : q1;
        f1.x = hi ? q6 : p4;  f1.y = hi ? q7 : p5;  f1.z = hi ? p6 : q4;  f1.w = hi ? p7 : q5;
    };

    // ---- prologue: phase A chunk crot -> HsF[par=0]; W2(crot) prefetch; barrier ----
    {
        const int cc = crot;
        const unsigned short* w1p = W1F + ((size_t)(cc * 4 + w) * 8) * 512 + lane * 8;
        float4 bq[4];
        #pragma unroll
        for (int q = 0; q < 4; ++q) bq[q] = *(const float4*)&b1[cc * 128 + w * 32 + 8 * q + 4 * hi];
        #pragma unroll
        for (int r = 0; r < 16; ++r) { h0[r] = 0.0f; h1[r] = 0.0f; }
        #pragma unroll
        for (int ks = 0; ks < 8; ++ks) {
            bf16x8 wfr = *(const bf16x8*)(w1p + ks * 512);
            bf16x8 x0 = *(const bf16x8*)&Xsf[((0 * 8 + ks) * 64 + lane) * 8];
            bf16x8 x1 = *(const bf16x8*)&Xsf[((1 * 8 + ks) * 64 + lane) * 8];
            h0 = __builtin_amdgcn_mfma_f32_32x32x16_bf16(wfr, x0, h0, 0, 0, 0);
            h1 = __builtin_amdgcn_mfma_f32_32x32x16_bf16(wfr, x1, h1, 0, 0, 0);
        }
        packswap(h0, bq, f00, f01);
        packswap(h1, bq, f10, f11);
        unsigned short* hw = &HsF[0];
        *(uint4*)&hw[((0 * 8 + 2 * w + 0) * 64 + lane) * 8] = f00;
        *(uint4*)&hw[((0 * 8 + 2 * w + 1) * 64 + lane) * 8] = f01;
        *(uint4*)&hw[((1 * 8 + 2 * w + 0) * 64 + lane) * 8] = f10;
        *(uint4*)&hw[((1 * 8 + 2 * w + 1) * 64 + lane) * 8] = f11;
        // W2(crot) prefetch into regs: issued before barrier, stays in flight across it
        const unsigned short* w2p0 = W2F + ((size_t)(2 * w + 0) * 64 + cc * 8) * 512 + lane * 8;
        const unsigned short* w2p1 = W2F + ((size_t)(2 * w + 1) * 64 + cc * 8) * 512 + lane * 8;
        #pragma unroll
        for (int kc = 0; kc < 8; ++kc) {
            wf2r[kc]     = *(const float4*)(w2p0 + kc * 512);
            wf2r[8 + kc] = *(const float4*)(w2p1 + kc * 512);
        }
        asm volatile("s_waitcnt lgkmcnt(0)" ::: "memory");   // my ds writes retired
        __builtin_amdgcn_s_barrier();
    }

    // ---- main loop: one barrier per chunk; all LDS lane-linear (zero conflicts) ----
    for (int i = 0; i < 8; ++i) {
        const int par = i & 1;
        const int cn  = (crot + i + 1) & 7;

        float4 wf1f[8];
        float4 bq[4];
        if (i < 7) {
            // issue W1(cn)+bias loads at region top: latency hides under phase B
            const unsigned short* w1p = W1F + ((size_t)(cn * 4 + w) * 8) * 512 + lane * 8;
            #pragma unroll
            for (int ks = 0; ks < 8; ++ks) wf1f[ks] = *(const float4*)(w1p + ks * 512);
            #pragma unroll
            for (int q = 0; q < 4; ++q) bq[q] = *(const float4*)&b1[cn * 128 + w * 32 + 8 * q + 4 * hi];
        }

        // ---- phase B, chunk cc=(crot+i)&7: own kc pair from regs, rest from LDS ----
        {
            const unsigned short* hbase = &HsF[(size_t)par * 8192];
            #pragma unroll
            for (int p = 0; p < 4; ++p) {          // kc pair p = {2p, 2p+1}
                bf16x8 a00, a01, a10, a11;         // (mi, jj)
                if (p == wu) {
                    a00 = __builtin_bit_cast(bf16x8, f00);
                    a01 = __builtin_bit_cast(bf16x8, f01);
                    a10 = __builtin_bit_cast(bf16x8, f10);
                    a11 = __builtin_bit_cast(bf16x8, f11);
                } else {
                    a00 = *(const bf16x8*)&hbase[((0 * 8 + 2 * p + 0) * 64 + lane) * 8];
                    a01 = *(const bf16x8*)&hbase[((0 * 8 + 2 * p + 1) * 64 + lane) * 8];
                    a10 = *(const bf16x8*)&hbase[((1 * 8 + 2 * p + 0) * 64 + lane) * 8];
                    a11 = *(const bf16x8*)&hbase[((1 * 8 + 2 * p + 1) * 64 + lane) * 8];
                }
                bf16x8 b00 = __builtin_bit_cast(bf16x8, wf2r[2 * p + 0]);
                bf16x8 b01 = __builtin_bit_cast(bf16x8, wf2r[2 * p + 1]);
                bf16x8 b10 = __builtin_bit_cast(bf16x8, wf2r[8 + 2 * p + 0]);
                bf16x8 b11 = __builtin_bit_cast(bf16x8, wf2r[8 + 2 * p + 1]);
                acc[0][0] = __builtin_amdgcn_mfma_f32_32x32x16_bf16(a00, b00, acc[0][0], 0, 0, 0);
                acc[0][1] = __builtin_amdgcn_mfma_f32_32x32x16_bf16(a00, b10, acc[0][1], 0, 0, 0);
                acc[1][0] = __builtin_amdgcn_mfma_f32_32x32x16_bf16(a10, b00, acc[1][0], 0, 0, 0);
                acc[1][1] = __builtin_amdgcn_mfma_f32_32x32x16_bf16(a10, b10, acc[1][1], 0, 0, 0);
                acc[0][0] = __builtin_amdgcn_mfma_f32_32x32x16_bf16(a01, b01, acc[0][0], 0, 0, 0);
                acc[0][1] = __builtin_amdgcn_mfma_f32_32x32x16_bf16(a01, b11, acc[0][1], 0, 0, 0);
                acc[1][0] = __builtin_amdgcn_mfma_f32_32x32x16_bf16(a11, b01, acc[1][0], 0, 0, 0);
                acc[1][1] = __builtin_amdgcn_mfma_f32_32x32x16_bf16(a11, b11, acc[1][1], 0, 0, 0);
            }
        }

        if (i < 7) {
            // W2(cn) prefetch into regs: after last wf2r use, before the barrier
            const unsigned short* w2p0 = W2F + ((size_t)(2 * w + 0) * 64 + cn * 8) * 512 + lane * 8;
            const unsigned short* w2p1 = W2F + ((size_t)(2 * w + 1) * 64 + cn * 8) * 512 + lane * 8;
            #pragma unroll
            for (int kc = 0; kc < 8; ++kc) {
                wf2r[kc]     = *(const float4*)(w2p0 + kc * 512);
                wf2r[8 + kc] = *(const float4*)(w2p1 + kc * 512);
            }

            // ---- phase A, chunk cn ----
            #pragma unroll
            for (int r = 0; r < 16; ++r) { h0[r] = 0.0f; h1[r] = 0.0f; }
            #pragma unroll
            for (int ks = 0; ks < 8; ++ks) {
                bf16x8 wfr = __builtin_bit_cast(bf16x8, wf1f[ks]);
                bf16x8 x0 = *(const bf16x8*)&Xsf[((0 * 8 + ks) * 64 + lane) * 8];
                bf16x8 x1 = *(const bf16x8*)&Xsf[((1 * 8 + ks) * 64 + lane) * 8];
                h0 = __builtin_amdgcn_mfma_f32_32x32x16_bf16(wfr, x0, h0, 0, 0, 0);
                h1 = __builtin_amdgcn_mfma_f32_32x32x16_bf16(wfr, x1, h1, 0, 0, 0);
            }
            packswap(h0, bq, f00, f01);
            packswap(h1, bq, f10, f11);
            // write H(cn) -> HsF[par^1]; anti-dep vs other waves' reads of this buffer
            // (iteration i-1) is ordered by the previous barrier.
            unsigned short* hw = &HsF[(size_t)(par ^ 1) * 8192];
            *(uint4*)&hw[((0 * 8 + 2 * w + 0) * 64 + lane) * 8] = f00;
            *(uint4*)&hw[((0 * 8 + 2 * w + 1) * 64 + lane) * 8] = f01;
            *(uint4*)&hw[((1 * 8 + 2 * w + 0) * 64 + lane) * 8] = f10;
            *(uint4*)&hw[((1 * 8 + 2 * w + 1) * 64 + lane) * 8] = f11;

            asm volatile("s_waitcnt lgkmcnt(0)" ::: "memory");   // my ds reads+writes retired
            __builtin_amdgcn_s_barrier();                        // vmcnt NOT drained
        }
    }

    // ---- epilogue: + b2, store f32 ----
    #pragma unroll
    for (int ni = 0; ni < 2; ++ni) {
        const int col = (2 * w + ni) * 32 + l32;
        const float bb = b2[col];
        #pragma unroll
        for (int mi = 0; mi < 2; ++mi) {
            #pragma unroll
            for (int r = 0; r < 16; ++r) {
                const long row = r0 + mi * 32 + (r & 3) + 8 * (r >> 2) + 4 * hi;
                out[row * 256 + col] = acc[mi][ni][r] + bb;
            }
        }
    }
}

extern "C" void kernel_launch(void* const* d_in, const int* in_sizes, int n_in,
                              void* d_out, int out_size, void* d_ws, size_t ws_size,
                              hipStream_t stream) {
    (void)in_sizes; (void)n_in; (void)out_size; (void)ws_size;
    const float* hole  = (const float*)d_in[0];
    const float* board = (const float*)d_in[1];
    const float* W1    = (const float*)d_in[2];
    const float* b1    = (const float*)d_in[3];
    const float* W2    = (const float*)d_in[4];
    const float* b2    = (const float*)d_in[5];
    float* out = (float*)d_out;

    unsigned short* W1F = (unsigned short*)d_ws;            // 131072 bf16 = 256 KB
    unsigned short* W2F = W1F + 131072;                     // 262144 bf16 = 512 KB

    conv_w<<<1536, 256, 0, stream>>>(W1, W2, W1F, W2F);
    mlp_fused<<<131072 / 64, 256, 0, stream>>>(hole, board, b1, b2, W1F, W2F, out);
}